// Round 3
// baseline (98.495 us; speedup 1.0000x reference)
//
#include <hip/hip_runtime.h>
#include <hip/hip_bf16.h>

#define DD 128
#define NN 512
#define BB 4

// ---------------------------------------------------------------------------
// Kernel 1: prep.  cb[b][d] = b1[d] + E0@W1a + nc@W1b + te[t[b]]@W1c  (per batch)
//           v1[d] = (E1-E0)@W1a
// Grid: 2 blocks x 256 threads -> 512 threads = 4 batches x 128 d.
// ---------------------------------------------------------------------------
__global__ __launch_bounds__(256) void prep_kernel(
    const int* __restrict__ tt,
    const float* __restrict__ time_embed,
    const float* __restrict__ no_cond,
    const float* __restrict__ edge_embed,
    const float* __restrict__ W1,
    const float* __restrict__ b1,
    float* __restrict__ ws_cb,   // [4*128]
    float* __restrict__ ws_v1)   // [128]
{
    int g = blockIdx.x * 256 + threadIdx.x;   // 0..511
    int b = g >> 7;
    int d = g & 127;
    const float* te = time_embed + (size_t)tt[b] * DD;
    float c = b1[d];
    float v = 0.f;
#pragma unroll 4
    for (int k = 0; k < DD; ++k) {
        float w0 = W1[k * DD + d];
        c = fmaf(edge_embed[k], w0, c);
        c = fmaf(no_cond[k], W1[(DD + k) * DD + d], c);
        c = fmaf(te[k], W1[(2 * DD + k) * DD + d], c);
        v = fmaf(edge_embed[DD + k] - edge_embed[k], w0, v);
    }
    ws_cb[g] = c;
    if (b == 0) ws_v1[d] = v;
}

// ---------------------------------------------------------------------------
// Kernel 2: per-row pipeline. 256 blocks x 256 threads, 8 rows per block.
//  phase A: count ones in each adj row -> p[r]
//  phase B: preHf[r][c] = sum_d relu(cb[d]+p[r]*v1[d]) * W2[d][c]
//           d split into 8 chunks of 16 across thread groups; h recomputed
//           in-register; W2 read from global exactly once per block.
//  phase C: combine partials in LDS, relu(+b2), project onto Wc -> li/lj per row.
// ---------------------------------------------------------------------------
__global__ __launch_bounds__(256) void rows_kernel(
    const int* __restrict__ adj,
    const float* __restrict__ W2,
    const float* __restrict__ b2,
    const float* __restrict__ Wc,
    const float* __restrict__ ws_cb,
    const float* __restrict__ ws_v1,
    float* __restrict__ ws_li,   // [2048*2]
    float* __restrict__ ws_lj)   // [2048*2]
{
    __shared__ float sP[8 * 8 * DD];   // [r][dh][c] partial preHf, 32 KB
    __shared__ float s_cb[DD];
    __shared__ float s_v1[DD];
    __shared__ float s_p[8];

    const int t = threadIdx.x;
    const int row0 = blockIdx.x * 8;
    const int b = row0 >> 9;

    if (t < DD) s_cb[t] = ws_cb[b * DD + t];
    else        s_v1[t - DD] = ws_v1[t - DD];

    const int cg = t & 31;    // 0..31
    const int dh = t >> 5;    // 0..7

    // --- phase A: count ones. row r = dh handled by 32 lanes x 4 int4 ---
    {
        const int4* base = (const int4*)(adj + (size_t)(row0 + dh) * NN);
        int s = 0;
#pragma unroll
        for (int k = 0; k < 4; ++k) {
            int4 a = base[cg + 32 * k];
            s += a.x + a.y + a.z + a.w;
        }
#pragma unroll
        for (int off = 16; off; off >>= 1) s += __shfl_xor(s, off, 64);
        if (cg == 0) s_p[dh] = (float)s * (1.0f / (float)NN);
    }
    __syncthreads();

    float p[8];
#pragma unroll
    for (int r = 0; r < 8; ++r) p[r] = s_p[r];

    // --- phase B: partial matvec. thread = (col group cg -> c0..c0+3, d chunk dh) ---
    const int c0 = cg * 4;
    float acc[8][4];
#pragma unroll
    for (int r = 0; r < 8; ++r)
#pragma unroll
        for (int cc = 0; cc < 4; ++cc) acc[r][cc] = 0.f;

    const float4* W2v = (const float4*)W2;
#pragma unroll
    for (int i = 0; i < 16; ++i) {
        const int d = dh * 16 + i;
        float4 w = W2v[(d * DD + c0) >> 2];
        float cbd = s_cb[d];
        float v1d = s_v1[d];
#pragma unroll
        for (int r = 0; r < 8; ++r) {
            float h = fmaxf(fmaf(p[r], v1d, cbd), 0.f);
            acc[r][0] = fmaf(h, w.x, acc[r][0]);
            acc[r][1] = fmaf(h, w.y, acc[r][1]);
            acc[r][2] = fmaf(h, w.z, acc[r][2]);
            acc[r][3] = fmaf(h, w.w, acc[r][3]);
        }
    }
#pragma unroll
    for (int r = 0; r < 8; ++r) {
        float4 v = make_float4(acc[r][0], acc[r][1], acc[r][2], acc[r][3]);
        *(float4*)&sP[(r * 8 + dh) * DD + c0] = v;
    }
    __syncthreads();

    // --- phase C: combine.  thread -> (row = dh, cols c0..c0+3) ---
    float s0 = 0.f, s1 = 0.f, s2 = 0.f, s3 = 0.f;
#pragma unroll
    for (int k = 0; k < 8; ++k) {
        float4 v = *(const float4*)&sP[(dh * 8 + k) * DD + c0];
        s0 += v.x; s1 += v.y; s2 += v.z; s3 += v.w;
    }
    float4 bb = *(const float4*)&b2[c0];
    float f0 = fmaxf(s0 + bb.x, 0.f);
    float f1 = fmaxf(s1 + bb.y, 0.f);
    float f2 = fmaxf(s2 + bb.z, 0.f);
    float f3 = fmaxf(s3 + bb.w, 0.f);

    const float4* WcV = (const float4*)Wc;
    float4 wa0 = WcV[(c0 * 2) >> 2];            // Wc rows c0, c0+1
    float4 wa1 = WcV[(c0 * 2 + 4) >> 2];        // Wc rows c0+2, c0+3
    float4 wb0 = WcV[((DD + c0) * 2) >> 2];
    float4 wb1 = WcV[((DD + c0) * 2 + 4) >> 2];

    float li0 = f0 * wa0.x + f1 * wa0.z + f2 * wa1.x + f3 * wa1.z;
    float li1 = f0 * wa0.y + f1 * wa0.w + f2 * wa1.y + f3 * wa1.w;
    float lj0 = f0 * wb0.x + f1 * wb0.z + f2 * wb1.x + f3 * wb1.z;
    float lj1 = f0 * wb0.y + f1 * wb0.w + f2 * wb1.y + f3 * wb1.w;

#pragma unroll
    for (int off = 16; off; off >>= 1) {
        li0 += __shfl_xor(li0, off, 64);
        li1 += __shfl_xor(li1, off, 64);
        lj0 += __shfl_xor(lj0, off, 64);
        lj1 += __shfl_xor(lj1, off, 64);
    }
    if (cg == 0) {
        int row = row0 + dh;
        *(float2*)&ws_li[row * 2] = make_float2(li0, li1);
        *(float2*)&ws_lj[row * 2] = make_float2(lj0, lj1);
    }
}

// ---------------------------------------------------------------------------
// Kernel 3: logits[b,i,j,c] = li[b,i,c] + lj[b,j,c] + bc[c]  (f32 output)
// Grid: 1024 blocks x 256 threads. Block covers 2 i-rows; thread stores 8 f32.
// ---------------------------------------------------------------------------
__global__ __launch_bounds__(256) void write_kernel(
    const float* __restrict__ ws_li,
    const float* __restrict__ ws_lj,
    const float* __restrict__ bc,
    float* __restrict__ out)
{
    const int blk = blockIdx.x;           // 0..1023
    const int t = threadIdx.x;
    const int b = blk >> 8;
    const int i = (blk & 255) * 2 + (t >> 7);
    const int j0 = (t & 127) * 4;

    float2 li = *(const float2*)&ws_li[(b * NN + i) * 2];
    float a0 = li.x + bc[0];
    float a1 = li.y + bc[1];

    float4 L0 = *(const float4*)&ws_lj[(b * NN + j0) * 2];       // rows j0, j0+1
    float4 L1 = *(const float4*)&ws_lj[(b * NN + j0 + 2) * 2];   // rows j0+2, j0+3

    float4 o0 = make_float4(a0 + L0.x, a1 + L0.y, a0 + L0.z, a1 + L0.w);
    float4 o1 = make_float4(a0 + L1.x, a1 + L1.y, a0 + L1.z, a1 + L1.w);

    size_t base = (((size_t)(b * NN + i)) * NN + j0) * 2;   // f32 element index
    *(float4*)&out[base]     = o0;
    *(float4*)&out[base + 4] = o1;
}

extern "C" void kernel_launch(void* const* d_in, const int* in_sizes, int n_in,
                              void* d_out, int out_size, void* d_ws, size_t ws_size,
                              hipStream_t stream) {
    const int*   adj = (const int*)d_in[0];
    const int*   tt  = (const int*)d_in[1];
    const float* te  = (const float*)d_in[2];
    const float* nc  = (const float*)d_in[3];
    const float* ee  = (const float*)d_in[4];
    const float* W1  = (const float*)d_in[5];
    const float* b1  = (const float*)d_in[6];
    const float* W2  = (const float*)d_in[7];
    const float* b2  = (const float*)d_in[8];
    const float* Wc  = (const float*)d_in[9];
    const float* bc  = (const float*)d_in[10];
    float* out = (float*)d_out;

    float* ws    = (float*)d_ws;
    float* ws_cb = ws;            // 512 floats
    float* ws_v1 = ws + 512;      // 128 floats
    float* ws_li = ws + 1024;     // 4096 floats
    float* ws_lj = ws + 5120;     // 4096 floats  (total 36 KB of ws)

    prep_kernel<<<2, 256, 0, stream>>>(tt, te, nc, ee, W1, b1, ws_cb, ws_v1);
    rows_kernel<<<256, 256, 0, stream>>>(adj, W2, b2, Wc, ws_cb, ws_v1, ws_li, ws_lj);
    write_kernel<<<1024, 256, 0, stream>>>(ws_li, ws_lj, bc, out);
}

// Round 4
// 97.364 us; speedup vs baseline: 1.0116x; 1.0116x over previous
//
#include <hip/hip_runtime.h>
#include <hip/hip_bf16.h>

#define DD 128
#define NN 512
#define BB 4

// ---------------------------------------------------------------------------
// Kernel 1: fused prep + per-row pipeline. 256 blocks x 256 threads, 8 rows/blk.
//  phase P: each block redundantly computes cb[b][d] = b1[d] + E0@W1a + nc@W1b
//           + te[t[b]]@W1c  and  v1[d] = (E1-E0)@W1a.  Split across h = t>>7
//           (wave-uniform branch), reduced via LDS.  ~256 FMA/thread, W1 from L2.
//  phase A: count ones in each adj row -> p[r]  (overlaps phase P loads)
//  phase B: preHf[r][c] = sum_d relu(cb[d]+p[r]*v1[d]) * W2[d][c]
//           d split into 8 chunks of 16 across thread groups; h recomputed
//           in-register; W2 read from global exactly once per block.
//  phase C: combine partials in LDS, relu(+b2), project onto Wc -> li/lj per
//           row; bc folded into li here so the writer is pure add.
// ---------------------------------------------------------------------------
__global__ __launch_bounds__(256) void rows_kernel(
    const int* __restrict__ adj,
    const int* __restrict__ tt,
    const float* __restrict__ time_embed,
    const float* __restrict__ no_cond,
    const float* __restrict__ edge_embed,
    const float* __restrict__ W1,
    const float* __restrict__ b1,
    const float* __restrict__ W2,
    const float* __restrict__ b2,
    const float* __restrict__ Wc,
    const float* __restrict__ bc,
    float* __restrict__ ws_li,   // [2048*2]  (bc pre-added)
    float* __restrict__ ws_lj)   // [2048*2]
{
    __shared__ float sP[8 * 8 * DD];   // [r][dh][c] partial preHf, 32 KB
    __shared__ float s_cb[DD];
    __shared__ float s_v1[DD];
    __shared__ float s_p[8];
    __shared__ float s_rc[256];
    __shared__ float s_rv[256];

    const int t = threadIdx.x;
    const int row0 = blockIdx.x * 8;
    const int b = blockIdx.x >> 6;

    // --- phase P: partial cb / v1 (h = wave-uniform half selector) ---
    {
        const int d = t & 127;
        const int h = t >> 7;
        const float* teb = time_embed + (size_t)tt[b] * DD;
        float c = 0.f, v = 0.f;
        if (h == 0) {
#pragma unroll 4
            for (int k = 0; k < 128; ++k)
                c = fmaf(edge_embed[k], W1[k * DD + d], c);
#pragma unroll 4
            for (int k = 0; k < 64; ++k)
                c = fmaf(no_cond[k], W1[(128 + k) * DD + d], c);
#pragma unroll 4
            for (int k = 64; k < 128; ++k)
                v = fmaf(edge_embed[DD + k] - edge_embed[k], W1[k * DD + d], v);
        } else {
#pragma unroll 4
            for (int k = 64; k < 128; ++k)
                c = fmaf(no_cond[k], W1[(128 + k) * DD + d], c);
#pragma unroll 4
            for (int k = 0; k < 128; ++k)
                c = fmaf(teb[k], W1[(256 + k) * DD + d], c);
#pragma unroll 4
            for (int k = 0; k < 64; ++k)
                v = fmaf(edge_embed[DD + k] - edge_embed[k], W1[k * DD + d], v);
        }
        s_rc[t] = c;
        s_rv[t] = v;
    }

    const int cg = t & 31;    // 0..31
    const int dh = t >> 5;    // 0..7

    // --- phase A: count ones. row r = dh handled by 32 lanes x 4 int4 ---
    {
        const int4* base = (const int4*)(adj + (size_t)(row0 + dh) * NN);
        int s = 0;
#pragma unroll
        for (int k = 0; k < 4; ++k) {
            int4 a = base[cg + 32 * k];
            s += a.x + a.y + a.z + a.w;
        }
#pragma unroll
        for (int off = 16; off; off >>= 1) s += __shfl_xor(s, off, 64);
        if (cg == 0) s_p[dh] = (float)s * (1.0f / (float)NN);
    }
    __syncthreads();

    if (t < DD) {
        s_cb[t] = s_rc[t] + s_rc[t + 128] + b1[t];
        s_v1[t] = s_rv[t] + s_rv[t + 128];
    }
    __syncthreads();

    float p[8];
#pragma unroll
    for (int r = 0; r < 8; ++r) p[r] = s_p[r];

    // --- phase B: partial matvec. thread = (col group cg -> c0..c0+3, d chunk dh) ---
    const int c0 = cg * 4;
    float acc[8][4];
#pragma unroll
    for (int r = 0; r < 8; ++r)
#pragma unroll
        for (int cc = 0; cc < 4; ++cc) acc[r][cc] = 0.f;

    const float4* W2v = (const float4*)W2;
#pragma unroll
    for (int i = 0; i < 16; ++i) {
        const int d = dh * 16 + i;
        float4 w = W2v[(d * DD + c0) >> 2];
        float cbd = s_cb[d];
        float v1d = s_v1[d];
#pragma unroll
        for (int r = 0; r < 8; ++r) {
            float h = fmaxf(fmaf(p[r], v1d, cbd), 0.f);
            acc[r][0] = fmaf(h, w.x, acc[r][0]);
            acc[r][1] = fmaf(h, w.y, acc[r][1]);
            acc[r][2] = fmaf(h, w.z, acc[r][2]);
            acc[r][3] = fmaf(h, w.w, acc[r][3]);
        }
    }
#pragma unroll
    for (int r = 0; r < 8; ++r) {
        float4 v = make_float4(acc[r][0], acc[r][1], acc[r][2], acc[r][3]);
        *(float4*)&sP[(r * 8 + dh) * DD + c0] = v;
    }
    __syncthreads();

    // --- phase C: combine.  thread -> (row = dh, cols c0..c0+3) ---
    float s0 = 0.f, s1 = 0.f, s2 = 0.f, s3 = 0.f;
#pragma unroll
    for (int k = 0; k < 8; ++k) {
        float4 v = *(const float4*)&sP[(dh * 8 + k) * DD + c0];
        s0 += v.x; s1 += v.y; s2 += v.z; s3 += v.w;
    }
    float4 bb = *(const float4*)&b2[c0];
    float f0 = fmaxf(s0 + bb.x, 0.f);
    float f1 = fmaxf(s1 + bb.y, 0.f);
    float f2 = fmaxf(s2 + bb.z, 0.f);
    float f3 = fmaxf(s3 + bb.w, 0.f);

    const float4* WcV = (const float4*)Wc;
    float4 wa0 = WcV[(c0 * 2) >> 2];            // Wc rows c0, c0+1
    float4 wa1 = WcV[(c0 * 2 + 4) >> 2];        // Wc rows c0+2, c0+3
    float4 wb0 = WcV[((DD + c0) * 2) >> 2];
    float4 wb1 = WcV[((DD + c0) * 2 + 4) >> 2];

    float li0 = f0 * wa0.x + f1 * wa0.z + f2 * wa1.x + f3 * wa1.z;
    float li1 = f0 * wa0.y + f1 * wa0.w + f2 * wa1.y + f3 * wa1.w;
    float lj0 = f0 * wb0.x + f1 * wb0.z + f2 * wb1.x + f3 * wb1.z;
    float lj1 = f0 * wb0.y + f1 * wb0.w + f2 * wb1.y + f3 * wb1.w;

#pragma unroll
    for (int off = 16; off; off >>= 1) {
        li0 += __shfl_xor(li0, off, 64);
        li1 += __shfl_xor(li1, off, 64);
        lj0 += __shfl_xor(lj0, off, 64);
        lj1 += __shfl_xor(lj1, off, 64);
    }
    if (cg == 0) {
        int row = row0 + dh;
        *(float2*)&ws_li[row * 2] = make_float2(li0 + bc[0], li1 + bc[1]);
        *(float2*)&ws_lj[row * 2] = make_float2(lj0, lj1);
    }
}

// ---------------------------------------------------------------------------
// Kernel 2: logits[b,i,j,c] = li[b,i,c] + lj[b,j,c]   (bc pre-folded into li)
// Grid: 1024 blocks x 256 threads. Block covers 2 i-rows; thread stores 8 f32.
// ---------------------------------------------------------------------------
__global__ __launch_bounds__(256) void write_kernel(
    const float* __restrict__ ws_li,
    const float* __restrict__ ws_lj,
    float* __restrict__ out)
{
    const int blk = blockIdx.x;           // 0..1023
    const int t = threadIdx.x;
    const int b = blk >> 8;
    const int i = (blk & 255) * 2 + (t >> 7);
    const int j0 = (t & 127) * 4;

    float2 li = *(const float2*)&ws_li[(b * NN + i) * 2];
    float a0 = li.x;
    float a1 = li.y;

    float4 L0 = *(const float4*)&ws_lj[(b * NN + j0) * 2];       // rows j0, j0+1
    float4 L1 = *(const float4*)&ws_lj[(b * NN + j0 + 2) * 2];   // rows j0+2, j0+3

    float4 o0 = make_float4(a0 + L0.x, a1 + L0.y, a0 + L0.z, a1 + L0.w);
    float4 o1 = make_float4(a0 + L1.x, a1 + L1.y, a0 + L1.z, a1 + L1.w);

    size_t base = (((size_t)(b * NN + i)) * NN + j0) * 2;   // f32 element index
    *(float4*)&out[base]     = o0;
    *(float4*)&out[base + 4] = o1;
}

extern "C" void kernel_launch(void* const* d_in, const int* in_sizes, int n_in,
                              void* d_out, int out_size, void* d_ws, size_t ws_size,
                              hipStream_t stream) {
    const int*   adj = (const int*)d_in[0];
    const int*   tt  = (const int*)d_in[1];
    const float* te  = (const float*)d_in[2];
    const float* nc  = (const float*)d_in[3];
    const float* ee  = (const float*)d_in[4];
    const float* W1  = (const float*)d_in[5];
    const float* b1  = (const float*)d_in[6];
    const float* W2  = (const float*)d_in[7];
    const float* b2  = (const float*)d_in[8];
    const float* Wc  = (const float*)d_in[9];
    const float* bc  = (const float*)d_in[10];
    float* out = (float*)d_out;

    float* ws    = (float*)d_ws;
    float* ws_li = ws;            // 4096 floats
    float* ws_lj = ws + 4096;     // 4096 floats

    rows_kernel<<<256, 256, 0, stream>>>(adj, tt, te, nc, ee, W1, b1, W2, b2,
                                         Wc, bc, ws_li, ws_lj);
    write_kernel<<<1024, 256, 0, stream>>>(ws_li, ws_lj, out);
}